// Round 1
// baseline (394.361 us; speedup 1.0000x reference)
//
#include <hip/hip_runtime.h>
#include <math.h>

// Problem: B=256, A=16 -> N=4096 tokens; EMBED=1024, HIDDEN=1024, PROJ=256.
// Pipeline: h = gelu(x@w1+b1); p = h@w2+b2; z = p/||p||;
//           logits = (z@z^T)*exp(ls)+lb; loss = -(1/N) * sum log_sigmoid(m1*logits)
// d_out layout (fp32, return order): z [4096*256] | loss [1] | logits [4096*4096]
// d_ws layout: H [16 MiB] | Pbuf split-K x4 [16 MiB] | double loss acc [8 B]
//   (requires ws_size >= 33,554,440 bytes)

#define NTOK 4096
#define DEMB 1024
#define DHID 1024
#define DPRJ 256

static __device__ __forceinline__ float gelu_exact(float v) {
    return 0.5f * v * (1.0f + erff(v * 0.70710678118654752440f));
}
static __device__ __forceinline__ float log_sigmoid(float x) {
    // -log(1+exp(-x)), numerically stable
    return fminf(x, 0.0f) - log1pf(expf(-fabsf(x)));
}

// ---------------------------------------------------------------------------
// GEMM1: H = gelu(X @ W1 + b1).  X[4096,1024], W1[1024,1024] row-major.
// BM=128, BN=64, BK=16, 256 threads, 8x4 micro-tile (rows split 4+4 across
// the 64-row halves for conflict-free LDS reads).
// ---------------------------------------------------------------------------
__global__ __launch_bounds__(256, 2)
void k_gemm1_gelu(const float* __restrict__ X, const float* __restrict__ W1,
                  const float* __restrict__ B1, float* __restrict__ H)
{
    __shared__ float As[16][132];   // A transposed: As[k][m], stride 132 (pad 4)
    __shared__ float Bs[16][68];    // Bs[k][n], stride 68

    const int t  = threadIdx.x;
    const int bm = blockIdx.x * 128;
    const int bn = blockIdx.y * 64;
    const int tx = t & 15, ty = t >> 4;
    const int a_m = t >> 2;             // 0..63
    const int a_c = (t & 3) << 2;       // k sub-col group {0,4,8,12}
    const int b_k = t >> 4;             // 0..15
    const int b_n = (t & 15) << 2;      // 0..60

    float acc[8][4];
#pragma unroll
    for (int i = 0; i < 8; ++i)
#pragma unroll
        for (int j = 0; j < 4; ++j) acc[i][j] = 0.0f;

    const float* xp0 = &X[(size_t)(bm + a_m) * DEMB + a_c];
    const float* xp1 = xp0 + (size_t)64 * DEMB;
    const float* wp  = &W1[(size_t)b_k * DHID + bn + b_n];

    for (int kt = 0; kt < DEMB; kt += 16) {
        const float4 a0 = *(const float4*)(xp0 + kt);
        const float4 a1 = *(const float4*)(xp1 + kt);
        const float4 b0 = *(const float4*)(wp + (size_t)kt * DHID);
        __syncthreads();
        As[a_c + 0][a_m] = a0.x; As[a_c + 1][a_m] = a0.y;
        As[a_c + 2][a_m] = a0.z; As[a_c + 3][a_m] = a0.w;
        As[a_c + 0][a_m + 64] = a1.x; As[a_c + 1][a_m + 64] = a1.y;
        As[a_c + 2][a_m + 64] = a1.z; As[a_c + 3][a_m + 64] = a1.w;
        *(float4*)&Bs[b_k][b_n] = b0;
        __syncthreads();
#pragma unroll
        for (int k = 0; k < 16; ++k) {
            const float4 af0 = *(const float4*)&As[k][ty << 2];
            const float4 af1 = *(const float4*)&As[k][64 + (ty << 2)];
            const float4 bf  = *(const float4*)&Bs[k][tx << 2];
            const float am[8] = {af0.x, af0.y, af0.z, af0.w,
                                 af1.x, af1.y, af1.z, af1.w};
            const float bv[4] = {bf.x, bf.y, bf.z, bf.w};
#pragma unroll
            for (int i = 0; i < 8; ++i)
#pragma unroll
                for (int j = 0; j < 4; ++j)
                    acc[i][j] = fmaf(am[i], bv[j], acc[i][j]);
        }
    }

    const float4 bb = *(const float4*)&B1[bn + (tx << 2)];
    const float bv[4] = {bb.x, bb.y, bb.z, bb.w};
#pragma unroll
    for (int i = 0; i < 8; ++i) {
        const int row = bm + ((i < 4) ? ((ty << 2) + i) : (64 + (ty << 2) + (i - 4)));
        float4 o;
        o.x = gelu_exact(acc[i][0] + bv[0]);
        o.y = gelu_exact(acc[i][1] + bv[1]);
        o.z = gelu_exact(acc[i][2] + bv[2]);
        o.w = gelu_exact(acc[i][3] + bv[3]);
        *(float4*)&H[(size_t)row * DHID + bn + (tx << 2)] = o;
    }
}

// ---------------------------------------------------------------------------
// GEMM2 (split-K x4): Pbuf[kz] = H @ W2 over K-slice kz*256..+256.
// H[4096,1024], W2[1024,256]. Same tiling as GEMM1. No bias here.
// ---------------------------------------------------------------------------
__global__ __launch_bounds__(256, 2)
void k_gemm2_splitk(const float* __restrict__ Hm, const float* __restrict__ W2,
                    float* __restrict__ Pbuf)
{
    __shared__ float As[16][132];
    __shared__ float Bs[16][68];

    const int t  = threadIdx.x;
    const int bm = blockIdx.x * 128;
    const int bn = blockIdx.y * 64;
    const int kz = blockIdx.z;          // 0..3
    const int k0 = kz << 8;             // kz*256
    const int tx = t & 15, ty = t >> 4;
    const int a_m = t >> 2;
    const int a_c = (t & 3) << 2;
    const int b_k = t >> 4;
    const int b_n = (t & 15) << 2;

    float acc[8][4];
#pragma unroll
    for (int i = 0; i < 8; ++i)
#pragma unroll
        for (int j = 0; j < 4; ++j) acc[i][j] = 0.0f;

    const float* hp0 = &Hm[(size_t)(bm + a_m) * DHID + k0 + a_c];
    const float* hp1 = hp0 + (size_t)64 * DHID;
    const float* wp  = &W2[(size_t)(k0 + b_k) * DPRJ + bn + b_n];

    for (int kt = 0; kt < 256; kt += 16) {
        const float4 a0 = *(const float4*)(hp0 + kt);
        const float4 a1 = *(const float4*)(hp1 + kt);
        const float4 b0 = *(const float4*)(wp + (size_t)kt * DPRJ);
        __syncthreads();
        As[a_c + 0][a_m] = a0.x; As[a_c + 1][a_m] = a0.y;
        As[a_c + 2][a_m] = a0.z; As[a_c + 3][a_m] = a0.w;
        As[a_c + 0][a_m + 64] = a1.x; As[a_c + 1][a_m + 64] = a1.y;
        As[a_c + 2][a_m + 64] = a1.z; As[a_c + 3][a_m + 64] = a1.w;
        *(float4*)&Bs[b_k][b_n] = b0;
        __syncthreads();
#pragma unroll
        for (int k = 0; k < 16; ++k) {
            const float4 af0 = *(const float4*)&As[k][ty << 2];
            const float4 af1 = *(const float4*)&As[k][64 + (ty << 2)];
            const float4 bf  = *(const float4*)&Bs[k][tx << 2];
            const float am[8] = {af0.x, af0.y, af0.z, af0.w,
                                 af1.x, af1.y, af1.z, af1.w};
            const float bv[4] = {bf.x, bf.y, bf.z, bf.w};
#pragma unroll
            for (int i = 0; i < 8; ++i)
#pragma unroll
                for (int j = 0; j < 4; ++j)
                    acc[i][j] = fmaf(am[i], bv[j], acc[i][j]);
        }
    }

#pragma unroll
    for (int i = 0; i < 8; ++i) {
        const int row = bm + ((i < 4) ? ((ty << 2) + i) : (64 + (ty << 2) + (i - 4)));
        float4 o;
        o.x = acc[i][0]; o.y = acc[i][1]; o.z = acc[i][2]; o.w = acc[i][3];
        *(float4*)&Pbuf[((size_t)kz * NTOK + row) * DPRJ + bn + (tx << 2)] = o;
    }
}

// ---------------------------------------------------------------------------
// Row normalize: p = sum_kz Pbuf + b2; z = p / ||p||_2 -> d_out (embeddings).
// One block per row (256 threads = 256 cols). Also zeroes the loss acc.
// ---------------------------------------------------------------------------
__global__ __launch_bounds__(256)
void k_norm_rows(const float* __restrict__ Pbuf, const float* __restrict__ B2,
                 float* __restrict__ Z, double* __restrict__ lossacc)
{
    const int r = blockIdx.x;
    const int c = threadIdx.x;
    if (r == 0 && c == 0) *lossacc = 0.0;   // runs before gemm3 (same stream)

    float v = Pbuf[(size_t)r * DPRJ + c]
            + Pbuf[((size_t)NTOK     + r) * DPRJ + c]
            + Pbuf[((size_t)2 * NTOK + r) * DPRJ + c]
            + Pbuf[((size_t)3 * NTOK + r) * DPRJ + c]
            + B2[c];

    float ss = v * v;
#pragma unroll
    for (int o = 32; o > 0; o >>= 1) ss += __shfl_down(ss, o);
    __shared__ float wsum[4];
    if ((c & 63) == 0) wsum[c >> 6] = ss;
    __syncthreads();
    const float tot = wsum[0] + wsum[1] + wsum[2] + wsum[3];
    Z[(size_t)r * DPRJ + c] = v / sqrtf(tot);
}

// ---------------------------------------------------------------------------
// GEMM3: logits = (Z @ Z^T)*scale + bias; fused log-sigmoid loss reduction.
// Z[4096,256]. Both LDS tiles are transpose-loads of Z rows. BK=16, K=256.
// Logit stores are scalar (d_out logits region is only 4B-aligned).
// ---------------------------------------------------------------------------
__global__ __launch_bounds__(256, 2)
void k_gemm3_loss(const float* __restrict__ Z, const float* __restrict__ LS,
                  const float* __restrict__ LB, float* __restrict__ Lg,
                  double* __restrict__ lossacc)
{
    __shared__ float As[16][132];
    __shared__ float Bs[16][68];

    const int t  = threadIdx.x;
    const int bm = blockIdx.x * 128;    // 32 blocks
    const int bn = blockIdx.y * 64;     // 64 blocks
    const int tx = t & 15, ty = t >> 4;
    const int a_m = t >> 2;             // 0..63
    const int a_c = (t & 3) << 2;
    const int b_n = t >> 2;             // 0..63
    const int b_c = (t & 3) << 2;

    float acc[8][4];
#pragma unroll
    for (int i = 0; i < 8; ++i)
#pragma unroll
        for (int j = 0; j < 4; ++j) acc[i][j] = 0.0f;

    const float* ap0 = &Z[(size_t)(bm + a_m) * DPRJ + a_c];
    const float* ap1 = ap0 + (size_t)64 * DPRJ;
    const float* bp  = &Z[(size_t)(bn + b_n) * DPRJ + b_c];

    for (int kt = 0; kt < DPRJ; kt += 16) {
        const float4 a0 = *(const float4*)(ap0 + kt);
        const float4 a1 = *(const float4*)(ap1 + kt);
        const float4 b0 = *(const float4*)(bp + kt);
        __syncthreads();
        As[a_c + 0][a_m] = a0.x; As[a_c + 1][a_m] = a0.y;
        As[a_c + 2][a_m] = a0.z; As[a_c + 3][a_m] = a0.w;
        As[a_c + 0][a_m + 64] = a1.x; As[a_c + 1][a_m + 64] = a1.y;
        As[a_c + 2][a_m + 64] = a1.z; As[a_c + 3][a_m + 64] = a1.w;
        Bs[b_c + 0][b_n] = b0.x; Bs[b_c + 1][b_n] = b0.y;
        Bs[b_c + 2][b_n] = b0.z; Bs[b_c + 3][b_n] = b0.w;
        __syncthreads();
#pragma unroll
        for (int k = 0; k < 16; ++k) {
            const float4 af0 = *(const float4*)&As[k][ty << 2];
            const float4 af1 = *(const float4*)&As[k][64 + (ty << 2)];
            const float4 bf  = *(const float4*)&Bs[k][tx << 2];
            const float am[8] = {af0.x, af0.y, af0.z, af0.w,
                                 af1.x, af1.y, af1.z, af1.w};
            const float bv[4] = {bf.x, bf.y, bf.z, bf.w};
#pragma unroll
            for (int i = 0; i < 8; ++i)
#pragma unroll
                for (int j = 0; j < 4; ++j)
                    acc[i][j] = fmaf(am[i], bv[j], acc[i][j]);
        }
    }

    const float scale = expf(LS[0]);
    const float lbias = LB[0];
    float lsum = 0.0f;
#pragma unroll
    for (int i = 0; i < 8; ++i) {
        const int row = bm + ((i < 4) ? ((ty << 2) + i) : (64 + (ty << 2) + (i - 4)));
        const int rid = row >> 4;       // ids = token / 16
#pragma unroll
        for (int j = 0; j < 4; ++j) {
            const int col = bn + (tx << 2) + j;
            const float lg = fmaf(acc[i][j], scale, lbias);
            Lg[(size_t)row * NTOK + col] = lg;          // scalar store (4B-aligned dst)
            const float x = ((col >> 4) == rid) ? lg : -lg;
            lsum += log_sigmoid(x);
        }
    }

#pragma unroll
    for (int o = 32; o > 0; o >>= 1) lsum += __shfl_down(lsum, o);
    __shared__ float wsum[4];
    if ((t & 63) == 0) wsum[t >> 6] = lsum;
    __syncthreads();
    if (t == 0) {
        const double bs = (double)wsum[0] + (double)wsum[1]
                        + (double)wsum[2] + (double)wsum[3];
        atomicAdd(lossacc, bs);
    }
}

__global__ void k_finalize(const double* __restrict__ lossacc,
                           float* __restrict__ loss_out)
{
    loss_out[0] = (float)(-(*lossacc) / (double)NTOK);
}

// ---------------------------------------------------------------------------
extern "C" void kernel_launch(void* const* d_in, const int* in_sizes, int n_in,
                              void* d_out, int out_size, void* d_ws, size_t ws_size,
                              hipStream_t stream)
{
    const float* X  = (const float*)d_in[0];  // [256,16,1024] -> [4096,1024]
    const float* W1 = (const float*)d_in[1];  // [1024,1024]
    const float* B1 = (const float*)d_in[2];  // [1024]
    const float* W2 = (const float*)d_in[3];  // [1024,256]
    const float* B2 = (const float*)d_in[4];  // [256]
    const float* LS = (const float*)d_in[5];  // log_scale
    const float* LB = (const float*)d_in[6];  // logit_bias

    float* out  = (float*)d_out;
    float* Zo   = out;                               // embeddings [4096*256]
    float* loss = out + (size_t)NTOK * DPRJ;         // scalar
    float* Lg   = loss + 1;                          // logits [4096*4096]

    char*   ws   = (char*)d_ws;
    float*  Hbuf = (float*)ws;                                        // 16 MiB
    float*  Pbuf = (float*)(ws + (size_t)NTOK * DHID * 4);            // 16 MiB
    double* acc  = (double*)(ws + (size_t)NTOK * DHID * 4
                                + (size_t)4 * NTOK * DPRJ * 4);       // 8 B

    k_gemm1_gelu <<<dim3(32, 16),    256, 0, stream>>>(X, W1, B1, Hbuf);
    k_gemm2_splitk<<<dim3(32, 4, 4), 256, 0, stream>>>(Hbuf, W2, Pbuf);
    k_norm_rows  <<<dim3(4096),      256, 0, stream>>>(Pbuf, B2, Zo, acc);
    k_gemm3_loss <<<dim3(32, 64),    256, 0, stream>>>(Zo, LS, LB, Lg, acc);
    k_finalize   <<<1, 1, 0, stream>>>(acc, loss);
}

// Round 2
// 296.246 us; speedup vs baseline: 1.3312x; 1.3312x over previous
//
#include <hip/hip_runtime.h>
#include <math.h>

// B=256, A=16 -> N=4096 tokens; EMBED=HIDDEN=1024, PROJ=256.
// fp32 GEMMs emulated via bf16 hi/lo split MFMA (3-term: Ah*Bh + Ah*Bl + Al*Bh).
// d_out: z [4096*256] | loss [1] | logits [4096*4096]  (all fp32)
// d_ws layout (bytes):
//   Hh 0..8M | Hl 8M..16M | W1tH 16M..18M | W1tL | W2tH | W2tL
//   | Zbh | Zbl | P (fp32 4M) | double acc     -- total 30,408,712 B

#define NTOK 4096
#define DEMB 1024
#define DHID 1024
#define DPRJ 256

#define BK 32
#define PK 40   // padded LDS row length (bf16 elems): rows r,r+8 alias 2-way (free)

typedef __attribute__((ext_vector_type(8))) short bf16x8;
typedef __attribute__((ext_vector_type(4))) float f32x4;

static __device__ __forceinline__ ushort f2bf(float f) {
    uint u = __float_as_uint(f);
    return (ushort)((u + 0x7FFFu + ((u >> 16) & 1u)) >> 16);
}
static __device__ __forceinline__ float bf2f(ushort h) {
    return __uint_as_float(((uint)h) << 16);
}
static __device__ __forceinline__ float gelu_exact(float v) {
    return 0.5f * v * (1.0f + erff(v * 0.70710678118654752440f));
}
static __device__ __forceinline__ float log_sigmoid(float x) {
    return fminf(x, 0.0f) - log1pf(expf(-fabsf(x)));
}

// ---------------------------------------------------------------------------
// fp32 [K][N] -> bf16 hi/lo transposed [N][K]
// ---------------------------------------------------------------------------
__global__ __launch_bounds__(256)
void k_cvt_T(const float* __restrict__ W, ushort* __restrict__ WtH,
             ushort* __restrict__ WtL, int K, int N)
{
    const int idx = blockIdx.x * 256 + threadIdx.x;
    if (idx >= K * N) return;
    const int k = idx / N, n = idx - k * N;
    const float v = W[idx];
    const ushort h = f2bf(v);
    const ushort l = f2bf(v - bf2f(h));
    WtH[(size_t)n * K + k] = h;
    WtL[(size_t)n * K + k] = l;
}

// ---------------------------------------------------------------------------
// Staging helpers: 128 rows x 32 bf16 into padded LDS [row][PK]
// ---------------------------------------------------------------------------
static __device__ __forceinline__ void stage_u16(const ushort* __restrict__ G, int ld,
                                                 ushort* __restrict__ S, int t)
{
#pragma unroll
    for (int r = 0; r < 2; ++r) {
        const int s = t + 256 * r;            // 0..511
        const int row = s >> 2, c = s & 3;    // 4 chunks of 8 bf16 (16 B)
        const uint4 v = *(const uint4*)(G + (size_t)row * ld + c * 8);
        *(uint4*)(S + row * PK + c * 8) = v;
    }
}

static __device__ __forceinline__ void stage_f32_hilo(const float* __restrict__ G, int ld,
                                                      ushort* __restrict__ Sh,
                                                      ushort* __restrict__ Sl, int t)
{
#pragma unroll
    for (int r = 0; r < 2; ++r) {
        const int s = t + 256 * r;
        const int row = s >> 2, c = s & 3;    // 4 chunks of 8 floats (32 B)
        const float* p = G + (size_t)row * ld + c * 8;
        const float4 v0 = *(const float4*)p;
        const float4 v1 = *(const float4*)(p + 4);
        const float vv[8] = {v0.x, v0.y, v0.z, v0.w, v1.x, v1.y, v1.z, v1.w};
        uint4 hv, lv;
        ushort* hp = (ushort*)&hv;
        ushort* lp = (ushort*)&lv;
#pragma unroll
        for (int e = 0; e < 8; ++e) {
            const ushort h = f2bf(vv[e]);
            hp[e] = h;
            lp[e] = f2bf(vv[e] - bf2f(h));
        }
        *(uint4*)(Sh + row * PK + c * 8) = hv;
        *(uint4*)(Sl + row * PK + c * 8) = lv;
    }
}

// ---------------------------------------------------------------------------
// One BK=32 MFMA step: acc += Ah*Bh + Ah*Bl + Al*Bh  (3-term hi/lo fp32 emu)
// Fragment layout (mfma_f32_16x16x32_bf16): lane l: A[m=l&15][k=(l>>4)*8+e],
// B[k=(l>>4)*8+e][n=l&15]; C/D: col=l&15, row=(l>>4)*4+reg  (m89-verified).
// ---------------------------------------------------------------------------
static __device__ __forceinline__ void mma_step(const ushort* __restrict__ sAh,
                                                const ushort* __restrict__ sAl,
                                                const ushort* __restrict__ sBh,
                                                const ushort* __restrict__ sBl,
                                                int lane, int wr, int wc,
                                                f32x4 acc[4][4])
{
    const int lr = lane & 15, kb = lane >> 4;
    const int boff = (wc * 64 + lr) * PK + kb * 8;
    bf16x8 bh[4], bl[4];
#pragma unroll
    for (int j = 0; j < 4; ++j) {
        bh[j] = *(const bf16x8*)(sBh + boff + j * 16 * PK);
        bl[j] = *(const bf16x8*)(sBl + boff + j * 16 * PK);
    }
    const int aoff = (wr * 64 + lr) * PK + kb * 8;
#pragma unroll
    for (int i = 0; i < 4; ++i) {
        const bf16x8 ah = *(const bf16x8*)(sAh + aoff + i * 16 * PK);
        const bf16x8 al = *(const bf16x8*)(sAl + aoff + i * 16 * PK);
#pragma unroll
        for (int j = 0; j < 4; ++j) {
            acc[i][j] = __builtin_amdgcn_mfma_f32_16x16x32_bf16(ah, bh[j], acc[i][j], 0, 0, 0);
            acc[i][j] = __builtin_amdgcn_mfma_f32_16x16x32_bf16(ah, bl[j], acc[i][j], 0, 0, 0);
            acc[i][j] = __builtin_amdgcn_mfma_f32_16x16x32_bf16(al, bh[j], acc[i][j], 0, 0, 0);
        }
    }
}

#define GEMM_PRE()                                                       \
    __shared__ ushort sm[4 * 128 * PK];                                  \
    ushort* sAh = sm;                                                    \
    ushort* sAl = sm + 128 * PK;                                         \
    ushort* sBh = sm + 2 * 128 * PK;                                     \
    ushort* sBl = sm + 3 * 128 * PK;                                     \
    const int t = threadIdx.x, lane = t & 63, wv = t >> 6;               \
    const int wr = wv >> 1, wc = wv & 1;                                 \
    const int bm = blockIdx.x * 128, bn = blockIdx.y * 128;              \
    f32x4 acc[4][4];                                                     \
    _Pragma("unroll") for (int i = 0; i < 4; ++i)                        \
        _Pragma("unroll") for (int j = 0; j < 4; ++j)                    \
            acc[i][j] = (f32x4){0.0f, 0.0f, 0.0f, 0.0f};

// ---------------------------------------------------------------------------
// GEMM1: H = gelu(X @ W1 + b1) -> bf16 hi/lo.  X fp32 converted in staging.
// ---------------------------------------------------------------------------
__global__ __launch_bounds__(256, 2)
void k_gemm1(const float* __restrict__ X,
             const ushort* __restrict__ W1tH, const ushort* __restrict__ W1tL,
             const float* __restrict__ B1,
             ushort* __restrict__ Hh, ushort* __restrict__ Hl)
{
    GEMM_PRE();
    for (int kt = 0; kt < DEMB; kt += BK) {
        __syncthreads();
        stage_f32_hilo(X + (size_t)bm * DEMB + kt, DEMB, sAh, sAl, t);
        stage_u16(W1tH + (size_t)bn * DEMB + kt, DEMB, sBh, t);
        stage_u16(W1tL + (size_t)bn * DEMB + kt, DEMB, sBl, t);
        __syncthreads();
        mma_step(sAh, sAl, sBh, sBl, lane, wr, wc, acc);
    }
    const int lr = lane & 15, lq = lane >> 4;
#pragma unroll
    for (int j = 0; j < 4; ++j) {
        const int col = bn + wc * 64 + j * 16 + lr;
        const float b = B1[col];
#pragma unroll
        for (int i = 0; i < 4; ++i) {
#pragma unroll
            for (int e = 0; e < 4; ++e) {
                const int row = bm + wr * 64 + i * 16 + lq * 4 + e;
                const float g = gelu_exact(acc[i][j][e] + b);
                const ushort h = f2bf(g);
                Hh[(size_t)row * DHID + col] = h;
                Hl[(size_t)row * DHID + col] = f2bf(g - bf2f(h));
            }
        }
    }
}

// ---------------------------------------------------------------------------
// GEMM2: P = H @ W2 (fp32 out; bias added in norm kernel)
// ---------------------------------------------------------------------------
__global__ __launch_bounds__(256, 2)
void k_gemm2(const ushort* __restrict__ Hh, const ushort* __restrict__ Hl,
             const ushort* __restrict__ W2tH, const ushort* __restrict__ W2tL,
             float* __restrict__ P)
{
    GEMM_PRE();
    for (int kt = 0; kt < DHID; kt += BK) {
        __syncthreads();
        stage_u16(Hh + (size_t)bm * DHID + kt, DHID, sAh, t);
        stage_u16(Hl + (size_t)bm * DHID + kt, DHID, sAl, t);
        stage_u16(W2tH + (size_t)bn * DHID + kt, DHID, sBh, t);
        stage_u16(W2tL + (size_t)bn * DHID + kt, DHID, sBl, t);
        __syncthreads();
        mma_step(sAh, sAl, sBh, sBl, lane, wr, wc, acc);
    }
    const int lr = lane & 15, lq = lane >> 4;
#pragma unroll
    for (int j = 0; j < 4; ++j) {
        const int col = bn + wc * 64 + j * 16 + lr;
#pragma unroll
        for (int i = 0; i < 4; ++i) {
#pragma unroll
            for (int e = 0; e < 4; ++e) {
                const int row = bm + wr * 64 + i * 16 + lq * 4 + e;
                P[(size_t)row * DPRJ + col] = acc[i][j][e];
            }
        }
    }
}

// ---------------------------------------------------------------------------
// Row normalize: p = P + b2; z = p/||p||. Emits z fp32 + bf16 hi/lo. Zeroes acc.
// ---------------------------------------------------------------------------
__global__ __launch_bounds__(256)
void k_norm(const float* __restrict__ P, const float* __restrict__ B2,
            float* __restrict__ Zo, ushort* __restrict__ Zbh,
            ushort* __restrict__ Zbl, double* __restrict__ lossacc)
{
    const int r = blockIdx.x;
    const int c = threadIdx.x;
    if (r == 0 && c == 0) *lossacc = 0.0;   // completes before k_gemm3 (stream order)

    const float v = P[(size_t)r * DPRJ + c] + B2[c];
    float ss = v * v;
#pragma unroll
    for (int o = 32; o > 0; o >>= 1) ss += __shfl_down(ss, o);
    __shared__ float wsum[4];
    if ((c & 63) == 0) wsum[c >> 6] = ss;
    __syncthreads();
    const float tot = wsum[0] + wsum[1] + wsum[2] + wsum[3];
    const float z = v / sqrtf(tot);
    Zo[(size_t)r * DPRJ + c] = z;
    const ushort h = f2bf(z);
    Zbh[(size_t)r * DPRJ + c] = h;
    Zbl[(size_t)r * DPRJ + c] = f2bf(z - bf2f(h));
}

// ---------------------------------------------------------------------------
// GEMM3: logits = (Z @ Z^T)*scale + bias, fused log-sigmoid loss.
// A = Zb rows, B^T layout = Zb rows (same buffers).
// ---------------------------------------------------------------------------
__global__ __launch_bounds__(256, 2)
void k_gemm3(const ushort* __restrict__ Zbh, const ushort* __restrict__ Zbl,
             const float* __restrict__ LS, const float* __restrict__ LB,
             float* __restrict__ Lg, double* __restrict__ lossacc)
{
    GEMM_PRE();
    for (int kt = 0; kt < DPRJ; kt += BK) {
        __syncthreads();
        stage_u16(Zbh + (size_t)bm * DPRJ + kt, DPRJ, sAh, t);
        stage_u16(Zbl + (size_t)bm * DPRJ + kt, DPRJ, sAl, t);
        stage_u16(Zbh + (size_t)bn * DPRJ + kt, DPRJ, sBh, t);
        stage_u16(Zbl + (size_t)bn * DPRJ + kt, DPRJ, sBl, t);
        __syncthreads();
        mma_step(sAh, sAl, sBh, sBl, lane, wr, wc, acc);
    }

    const float scale = expf(LS[0]);
    const float lbias = LB[0];
    const int lr = lane & 15, lq = lane >> 4;
    float lsum = 0.0f;
#pragma unroll
    for (int j = 0; j < 4; ++j) {
        const int col = bn + wc * 64 + j * 16 + lr;
        const int cid = col >> 4;
#pragma unroll
        for (int i = 0; i < 4; ++i) {
#pragma unroll
            for (int e = 0; e < 4; ++e) {
                const int row = bm + wr * 64 + i * 16 + lq * 4 + e;
                const float lg = fmaf(acc[i][j][e], scale, lbias);
                Lg[(size_t)row * NTOK + col] = lg;   // 4B-aligned region, scalar store
                const float x = ((row >> 4) == cid) ? lg : -lg;
                lsum += log_sigmoid(x);
            }
        }
    }

#pragma unroll
    for (int o = 32; o > 0; o >>= 1) lsum += __shfl_down(lsum, o);
    __shared__ float wsum[4];
    if ((t & 63) == 0) wsum[t >> 6] = lsum;
    __syncthreads();
    if (t == 0) {
        const double bs = (double)wsum[0] + (double)wsum[1]
                        + (double)wsum[2] + (double)wsum[3];
        atomicAdd(lossacc, bs);
    }
}

__global__ void k_finalize(const double* __restrict__ lossacc,
                           float* __restrict__ loss_out)
{
    loss_out[0] = (float)(-(*lossacc) / (double)NTOK);
}

// ---------------------------------------------------------------------------
extern "C" void kernel_launch(void* const* d_in, const int* in_sizes, int n_in,
                              void* d_out, int out_size, void* d_ws, size_t ws_size,
                              hipStream_t stream)
{
    const float* X  = (const float*)d_in[0];
    const float* W1 = (const float*)d_in[1];
    const float* B1 = (const float*)d_in[2];
    const float* W2 = (const float*)d_in[3];
    const float* B2 = (const float*)d_in[4];
    const float* LS = (const float*)d_in[5];
    const float* LB = (const float*)d_in[6];

    float* out  = (float*)d_out;
    float* Zo   = out;
    float* loss = out + (size_t)NTOK * DPRJ;
    float* Lg   = loss + 1;

    char* ws = (char*)d_ws;
    ushort* Hh   = (ushort*)(ws);                         // 8,388,608 B
    ushort* Hl   = (ushort*)(ws + 8388608);               // 8,388,608
    ushort* W1tH = (ushort*)(ws + 16777216);              // 2,097,152
    ushort* W1tL = (ushort*)(ws + 18874368);              // 2,097,152
    ushort* W2tH = (ushort*)(ws + 20971520);              //   524,288
    ushort* W2tL = (ushort*)(ws + 21495808);              //   524,288
    ushort* Zbh  = (ushort*)(ws + 22020096);              // 2,097,152
    ushort* Zbl  = (ushort*)(ws + 24117248);              // 2,097,152
    float*  P    = (float*) (ws + 26214400);              // 4,194,304
    double* acc  = (double*)(ws + 30408704);              // 8

    k_cvt_T <<<dim3((DEMB * DHID) / 256), 256, 0, stream>>>(W1, W1tH, W1tL, DEMB, DHID);
    k_cvt_T <<<dim3((DHID * DPRJ) / 256), 256, 0, stream>>>(W2, W2tH, W2tL, DHID, DPRJ);
    k_gemm1 <<<dim3(32, 8),  256, 0, stream>>>(X, W1tH, W1tL, B1, Hh, Hl);
    k_gemm2 <<<dim3(32, 2),  256, 0, stream>>>(Hh, Hl, W2tH, W2tL, P);
    k_norm  <<<dim3(4096),   256, 0, stream>>>(P, B2, Zo, Zbh, Zbl, acc);
    k_gemm3 <<<dim3(32, 32), 256, 0, stream>>>(Zbh, Zbl, LS, LB, Lg, acc);
    k_finalize<<<1, 1, 0, stream>>>(acc, loss);
}

// Round 4
// 252.500 us; speedup vs baseline: 1.5618x; 1.1733x over previous
//
#include <hip/hip_runtime.h>
#include <math.h>

// B=256, A=16 -> N=4096 tokens; EMBED=HIDDEN=1024, PROJ=256.
// fp32 GEMMs emulated via bf16 hi/lo split MFMA (3 terms: Ah*Bh + Ah*Bl + Al*Bh).
// d_out: z [4096*256] | loss [1] | logits [4096*4096]  (fp32)
//
// d_ws layout (30,408,712 B total; lifetimes disjoint where aliased):
//   [ 0        ..  8388608) Hh                (written g1, read g2)
//   [ 8388608  .. 16777216) Hl                (written g1, read g2)
//   [16777216  .. 20971520) W1tH|W1tL         (written cvt, read g1, DEAD after g1)
//   [16777216  .. 25165824) P  split-K x2     (written g2, read norm)  -- aliases W1t
//   [25165824  .. 26214400) W2tH|W2tL         (written cvt, read g2)
//   [26214400  .. 28311552) Zbh               (written norm, read g3)
//   [28311552  .. 30408704) Zbl               (written norm, read g3)
//   [30408704  .. 30408712) double loss acc

#define NTOK 4096
#define DEMB 1024
#define DHID 1024
#define DPRJ 256
#define BK 32
#define PK 40   // padded LDS row (u16): 80B rows -> 2-way bank alias (free tier)

typedef __attribute__((ext_vector_type(8))) short bf16x8;
typedef __attribute__((ext_vector_type(4))) float f32x4;

static __device__ __forceinline__ ushort f2bf(float f) {
    uint u = __float_as_uint(f);
    return (ushort)((u + 0x7FFFu + ((u >> 16) & 1u)) >> 16);
}
static __device__ __forceinline__ float bf2f(ushort h) {
    return __uint_as_float(((uint)h) << 16);
}
// exact-GELU via A&S 7.1.26 rational erf (|err| <= 1.5e-7), hardware exp
static __device__ __forceinline__ float gelu_fast(float v) {
    const float x  = v * 0.70710678118654752440f;
    const float ax = fabsf(x);
    const float t  = 1.0f / (1.0f + 0.3275911f * ax);
    const float poly = t * (0.254829592f + t * (-0.284496736f + t * (1.421413741f
                     + t * (-1.453152027f + t * 1.061405429f))));
    const float erf_ax = 1.0f - poly * __expf(-ax * ax);
    return 0.5f * v * (1.0f + copysignf(erf_ax, x));
}
static __device__ __forceinline__ float log_sigmoid_fast(float x) {
    return fminf(x, 0.0f) - __logf(1.0f + __expf(-fabsf(x)));
}

// ---------------------------------------------------------------------------
// Tiled transpose+convert: fp32 [K][N] -> bf16 hi/lo [N][K]. 32x32 tiles.
// ---------------------------------------------------------------------------
__global__ __launch_bounds__(256)
void k_cvt_T(const float* __restrict__ W, ushort* __restrict__ WtH,
             ushort* __restrict__ WtL, int K, int N)
{
    __shared__ float tile[32][33];
    const int tn0 = blockIdx.x * 32;      // n-tile
    const int tk0 = blockIdx.y * 32;      // k-tile
    const int tr = threadIdx.x >> 5;      // 0..7
    const int tc = threadIdx.x & 31;
#pragma unroll
    for (int p = 0; p < 4; ++p)
        tile[tr + 8 * p][tc] = W[(size_t)(tk0 + tr + 8 * p) * N + tn0 + tc];
    __syncthreads();
#pragma unroll
    for (int p = 0; p < 4; ++p) {
        const int n = tr + 8 * p;
        const float v = tile[tc][n];      // transposed read (33-stride: conflict-free)
        const ushort h = f2bf(v);
        WtH[(size_t)(tn0 + n) * K + tk0 + tc] = h;
        WtL[(size_t)(tn0 + n) * K + tk0 + tc] = f2bf(v - bf2f(h));
    }
}

// ---------------------------------------------------------------------------
// Staging helpers (BK=32 columns, padded LDS [row][PK])
// ---------------------------------------------------------------------------
static __device__ __forceinline__ void stage_u16_128(const ushort* __restrict__ G, int ld,
                                                     ushort* __restrict__ S, int t)
{
#pragma unroll
    for (int r = 0; r < 2; ++r) {
        const int s = t + 256 * r;
        const int row = s >> 2, c = s & 3;
        *(uint4*)(S + row * PK + c * 8) = *(const uint4*)(G + (size_t)row * ld + c * 8);
    }
}
static __device__ __forceinline__ void stage_u16_64(const ushort* __restrict__ G, int ld,
                                                    ushort* __restrict__ S, int t)
{
    const int row = t >> 2, c = t & 3;
    *(uint4*)(S + row * PK + c * 8) = *(const uint4*)(G + (size_t)row * ld + c * 8);
}
static __device__ __forceinline__ void stage_f32_hilo_128(const float* __restrict__ G, int ld,
                                                          ushort* __restrict__ Sh,
                                                          ushort* __restrict__ Sl, int t)
{
#pragma unroll
    for (int r = 0; r < 2; ++r) {
        const int s = t + 256 * r;
        const int row = s >> 2, c = s & 3;
        const float* p = G + (size_t)row * ld + c * 8;
        const float4 v0 = *(const float4*)p;
        const float4 v1 = *(const float4*)(p + 4);
        const float vv[8] = {v0.x, v0.y, v0.z, v0.w, v1.x, v1.y, v1.z, v1.w};
        uint4 hv, lv;
        ushort* hp = (ushort*)&hv;
        ushort* lp = (ushort*)&lv;
#pragma unroll
        for (int e = 0; e < 8; ++e) {
            const ushort h = f2bf(vv[e]);
            hp[e] = h;
            lp[e] = f2bf(vv[e] - bf2f(h));
        }
        *(uint4*)(Sh + row * PK + c * 8) = hv;
        *(uint4*)(Sl + row * PK + c * 8) = lv;
    }
}

// ---------------------------------------------------------------------------
// MFMA inner steps (mfma_f32_16x16x32_bf16; C/D: col=lane&15, row=(lane>>4)*4+e)
// ---------------------------------------------------------------------------
static __device__ __forceinline__ void mma_64x32(const ushort* __restrict__ sAh,
                                                 const ushort* __restrict__ sAl,
                                                 const ushort* __restrict__ sBh,
                                                 const ushort* __restrict__ sBl,
                                                 int lane, int wr, int wc, f32x4 acc[4][2])
{
    const int lr = lane & 15, kb = lane >> 4;
    bf16x8 bh[2], bl[2];
    const int boff = (wc * 32 + lr) * PK + kb * 8;
#pragma unroll
    for (int j = 0; j < 2; ++j) {
        bh[j] = *(const bf16x8*)(sBh + boff + j * 16 * PK);
        bl[j] = *(const bf16x8*)(sBl + boff + j * 16 * PK);
    }
    const int aoff = (wr * 64 + lr) * PK + kb * 8;
#pragma unroll
    for (int i = 0; i < 4; ++i) {
        const bf16x8 ah = *(const bf16x8*)(sAh + aoff + i * 16 * PK);
        const bf16x8 al = *(const bf16x8*)(sAl + aoff + i * 16 * PK);
#pragma unroll
        for (int j = 0; j < 2; ++j) {
            acc[i][j] = __builtin_amdgcn_mfma_f32_16x16x32_bf16(ah, bh[j], acc[i][j], 0, 0, 0);
            acc[i][j] = __builtin_amdgcn_mfma_f32_16x16x32_bf16(ah, bl[j], acc[i][j], 0, 0, 0);
            acc[i][j] = __builtin_amdgcn_mfma_f32_16x16x32_bf16(al, bh[j], acc[i][j], 0, 0, 0);
        }
    }
}
static __device__ __forceinline__ void mma_64x64(const ushort* __restrict__ sAh,
                                                 const ushort* __restrict__ sAl,
                                                 const ushort* __restrict__ sBh,
                                                 const ushort* __restrict__ sBl,
                                                 int lane, int wr, int wc, f32x4 acc[4][4])
{
    const int lr = lane & 15, kb = lane >> 4;
    bf16x8 bh[4], bl[4];
    const int boff = (wc * 64 + lr) * PK + kb * 8;
#pragma unroll
    for (int j = 0; j < 4; ++j) {
        bh[j] = *(const bf16x8*)(sBh + boff + j * 16 * PK);
        bl[j] = *(const bf16x8*)(sBl + boff + j * 16 * PK);
    }
    const int aoff = (wr * 64 + lr) * PK + kb * 8;
#pragma unroll
    for (int i = 0; i < 4; ++i) {
        const bf16x8 ah = *(const bf16x8*)(sAh + aoff + i * 16 * PK);
        const bf16x8 al = *(const bf16x8*)(sAl + aoff + i * 16 * PK);
#pragma unroll
        for (int j = 0; j < 4; ++j) {
            acc[i][j] = __builtin_amdgcn_mfma_f32_16x16x32_bf16(ah, bh[j], acc[i][j], 0, 0, 0);
            acc[i][j] = __builtin_amdgcn_mfma_f32_16x16x32_bf16(ah, bl[j], acc[i][j], 0, 0, 0);
            acc[i][j] = __builtin_amdgcn_mfma_f32_16x16x32_bf16(al, bh[j], acc[i][j], 0, 0, 0);
        }
    }
}

// ---------------------------------------------------------------------------
// GEMM1: H = gelu(X @ W1 + b1) -> bf16 hi/lo. BM=128, BN=64 (grid 512 = 2/CU).
// ---------------------------------------------------------------------------
__global__ __launch_bounds__(256, 4)
void k_gemm1(const float* __restrict__ X,
             const ushort* __restrict__ W1tH, const ushort* __restrict__ W1tL,
             const float* __restrict__ B1,
             ushort* __restrict__ Hh, ushort* __restrict__ Hl)
{
    __shared__ ushort sm[(2 * 128 + 2 * 64) * PK];
    ushort* sAh = sm;
    ushort* sAl = sm + 128 * PK;
    ushort* sBh = sm + 2 * 128 * PK;
    ushort* sBl = sm + (2 * 128 + 64) * PK;
    const int t = threadIdx.x, lane = t & 63, wv = t >> 6;
    const int wr = wv >> 1, wc = wv & 1;
    const int bm = blockIdx.x * 128, bn = blockIdx.y * 64;

    f32x4 acc[4][2];
#pragma unroll
    for (int i = 0; i < 4; ++i)
#pragma unroll
        for (int j = 0; j < 2; ++j) acc[i][j] = (f32x4){0.f, 0.f, 0.f, 0.f};

    for (int kt = 0; kt < DEMB; kt += BK) {
        __syncthreads();
        stage_f32_hilo_128(X + (size_t)bm * DEMB + kt, DEMB, sAh, sAl, t);
        stage_u16_64(W1tH + (size_t)bn * DEMB + kt, DEMB, sBh, t);
        stage_u16_64(W1tL + (size_t)bn * DEMB + kt, DEMB, sBl, t);
        __syncthreads();
        mma_64x32(sAh, sAl, sBh, sBl, lane, wr, wc, acc);
    }

    const int lr = lane & 15, lq = lane >> 4;
#pragma unroll
    for (int j = 0; j < 2; ++j) {
        const int col = bn + wc * 32 + j * 16 + lr;
        const float b = B1[col];
#pragma unroll
        for (int i = 0; i < 4; ++i) {
#pragma unroll
            for (int e = 0; e < 4; ++e) {
                const int row = bm + wr * 64 + i * 16 + lq * 4 + e;
                const float g = gelu_fast(acc[i][j][e] + b);
                const ushort h = f2bf(g);
                Hh[(size_t)row * DHID + col] = h;
                Hl[(size_t)row * DHID + col] = f2bf(g - bf2f(h));
            }
        }
    }
}

// ---------------------------------------------------------------------------
// GEMM2 (split-K x2): Ppart[kz] = H @ W2 over K-half. BM=128, BN=64, grid 256.
// ---------------------------------------------------------------------------
__global__ __launch_bounds__(256, 4)
void k_gemm2(const ushort* __restrict__ Hh, const ushort* __restrict__ Hl,
             const ushort* __restrict__ W2tH, const ushort* __restrict__ W2tL,
             float* __restrict__ P)
{
    __shared__ ushort sm[(2 * 128 + 2 * 64) * PK];
    ushort* sAh = sm;
    ushort* sAl = sm + 128 * PK;
    ushort* sBh = sm + 2 * 128 * PK;
    ushort* sBl = sm + (2 * 128 + 64) * PK;
    const int t = threadIdx.x, lane = t & 63, wv = t >> 6;
    const int wr = wv >> 1, wc = wv & 1;
    const int bm = blockIdx.x * 128, bn = blockIdx.y * 64;
    const int k0 = blockIdx.z * 512;

    f32x4 acc[4][2];
#pragma unroll
    for (int i = 0; i < 4; ++i)
#pragma unroll
        for (int j = 0; j < 2; ++j) acc[i][j] = (f32x4){0.f, 0.f, 0.f, 0.f};

    for (int kt = 0; kt < 512; kt += BK) {
        __syncthreads();
        stage_u16_128(Hh + (size_t)bm * DHID + k0 + kt, DHID, sAh, t);
        stage_u16_128(Hl + (size_t)bm * DHID + k0 + kt, DHID, sAl, t);
        stage_u16_64(W2tH + (size_t)bn * DHID + k0 + kt, DHID, sBh, t);
        stage_u16_64(W2tL + (size_t)bn * DHID + k0 + kt, DHID, sBl, t);
        __syncthreads();
        mma_64x32(sAh, sAl, sBh, sBl, lane, wr, wc, acc);
    }

    float* Pz = P + (size_t)blockIdx.z * NTOK * DPRJ;
    const int lr = lane & 15, lq = lane >> 4;
#pragma unroll
    for (int j = 0; j < 2; ++j) {
        const int col = bn + wc * 32 + j * 16 + lr;
#pragma unroll
        for (int i = 0; i < 4; ++i) {
#pragma unroll
            for (int e = 0; e < 4; ++e) {
                const int row = bm + wr * 64 + i * 16 + lq * 4 + e;
                Pz[(size_t)row * DPRJ + col] = acc[i][j][e];
            }
        }
    }
}

// ---------------------------------------------------------------------------
// Row normalize: p = P0+P1+b2; z = p/||p||. Emits z fp32 + bf16 hi/lo; zeroes acc.
// ---------------------------------------------------------------------------
__global__ __launch_bounds__(256)
void k_norm(const float* __restrict__ P, const float* __restrict__ B2,
            float* __restrict__ Zo, ushort* __restrict__ Zbh,
            ushort* __restrict__ Zbl, double* __restrict__ lossacc)
{
    const int r = blockIdx.x;
    const int c = threadIdx.x;
    if (r == 0 && c == 0) *lossacc = 0.0;   // completes before k_gemm3 (stream order)

    const float v = P[(size_t)r * DPRJ + c]
                  + P[(size_t)NTOK * DPRJ + (size_t)r * DPRJ + c] + B2[c];
    float ss = v * v;
#pragma unroll
    for (int o = 32; o > 0; o >>= 1) ss += __shfl_down(ss, o);
    __shared__ float wsum[4];
    if ((c & 63) == 0) wsum[c >> 6] = ss;
    __syncthreads();
    const float tot = wsum[0] + wsum[1] + wsum[2] + wsum[3];
    const float z = v / sqrtf(tot);
    Zo[(size_t)r * DPRJ + c] = z;
    const ushort h = f2bf(z);
    Zbh[(size_t)r * DPRJ + c] = h;
    Zbl[(size_t)r * DPRJ + c] = f2bf(z - bf2f(h));
}

// ---------------------------------------------------------------------------
// GEMM3: logits = (Z @ Z^T)*scale + bias, fused fast log-sigmoid loss.
// BM=BN=128, grid 1024. Non-temporal logit stores.
// ---------------------------------------------------------------------------
__global__ __launch_bounds__(256, 3)
void k_gemm3(const ushort* __restrict__ Zbh, const ushort* __restrict__ Zbl,
             const float* __restrict__ LS, const float* __restrict__ LB,
             float* __restrict__ Lg, double* __restrict__ lossacc)
{
    __shared__ ushort sm[4 * 128 * PK];
    ushort* sAh = sm;
    ushort* sAl = sm + 128 * PK;
    ushort* sBh = sm + 2 * 128 * PK;
    ushort* sBl = sm + 3 * 128 * PK;
    const int t = threadIdx.x, lane = t & 63, wv = t >> 6;
    const int wr = wv >> 1, wc = wv & 1;
    const int bm = blockIdx.x * 128, bn = blockIdx.y * 128;

    f32x4 acc[4][4];
#pragma unroll
    for (int i = 0; i < 4; ++i)
#pragma unroll
        for (int j = 0; j < 4; ++j) acc[i][j] = (f32x4){0.f, 0.f, 0.f, 0.f};

    for (int kt = 0; kt < DPRJ; kt += BK) {
        __syncthreads();
        stage_u16_128(Zbh + (size_t)bm * DPRJ + kt, DPRJ, sAh, t);
        stage_u16_128(Zbl + (size_t)bm * DPRJ + kt, DPRJ, sAl, t);
        stage_u16_128(Zbh + (size_t)bn * DPRJ + kt, DPRJ, sBh, t);
        stage_u16_128(Zbl + (size_t)bn * DPRJ + kt, DPRJ, sBl, t);
        __syncthreads();
        mma_64x64(sAh, sAl, sBh, sBl, lane, wr, wc, acc);
    }

    const float scale = __expf(LS[0]);
    const float lbias = LB[0];
    const int lr = lane & 15, lq = lane >> 4;
    float lsum = 0.0f;
#pragma unroll
    for (int j = 0; j < 4; ++j) {
        const int col = bn + wc * 64 + j * 16 + lr;
        const int cid = col >> 4;
#pragma unroll
        for (int i = 0; i < 4; ++i) {
#pragma unroll
            for (int e = 0; e < 4; ++e) {
                const int row = bm + wr * 64 + i * 16 + lq * 4 + e;
                const float lg = fmaf(acc[i][j][e], scale, lbias);
                __builtin_nontemporal_store(lg, &Lg[(size_t)row * NTOK + col]);
                const float x = ((row >> 4) == cid) ? lg : -lg;
                lsum += log_sigmoid_fast(x);
            }
        }
    }

#pragma unroll
    for (int o = 32; o > 0; o >>= 1) lsum += __shfl_down(lsum, o);
    __shared__ float wsum[4];
    if ((t & 63) == 0) wsum[t >> 6] = lsum;
    __syncthreads();
    if (t == 0) {
        const double bs = (double)wsum[0] + (double)wsum[1]
                        + (double)wsum[2] + (double)wsum[3];
        atomicAdd(lossacc, bs);
    }
}

__global__ void k_finalize(const double* __restrict__ lossacc,
                           float* __restrict__ loss_out)
{
    loss_out[0] = (float)(-(*lossacc) / (double)NTOK);
}

// ---------------------------------------------------------------------------
extern "C" void kernel_launch(void* const* d_in, const int* in_sizes, int n_in,
                              void* d_out, int out_size, void* d_ws, size_t ws_size,
                              hipStream_t stream)
{
    const float* X  = (const float*)d_in[0];
    const float* W1 = (const float*)d_in[1];
    const float* B1 = (const float*)d_in[2];
    const float* W2 = (const float*)d_in[3];
    const float* B2 = (const float*)d_in[4];
    const float* LS = (const float*)d_in[5];
    const float* LB = (const float*)d_in[6];

    float* out  = (float*)d_out;
    float* Zo   = out;
    float* loss = out + (size_t)NTOK * DPRJ;
    float* Lg   = loss + 1;

    char* ws = (char*)d_ws;
    ushort* Hh   = (ushort*)(ws);                 //  8,388,608
    ushort* Hl   = (ushort*)(ws + 8388608);       //  8,388,608
    ushort* W1tH = (ushort*)(ws + 16777216);      //  2,097,152 (dead after g1)
    ushort* W1tL = (ushort*)(ws + 18874368);      //  2,097,152 (dead after g1)
    float*  P    = (float*) (ws + 16777216);      //  8,388,608 (aliases W1t; written g2)
    ushort* W2tH = (ushort*)(ws + 25165824);      //    524,288
    ushort* W2tL = (ushort*)(ws + 25690112);      //    524,288
    ushort* Zbh  = (ushort*)(ws + 26214400);      //  2,097,152
    ushort* Zbl  = (ushort*)(ws + 28311552);      //  2,097,152
    double* acc  = (double*)(ws + 30408704);      //          8

    k_cvt_T <<<dim3(32, 32),    256, 0, stream>>>(W1, W1tH, W1tL, DEMB, DHID);
    k_cvt_T <<<dim3(8, 32),     256, 0, stream>>>(W2, W2tH, W2tL, DHID, DPRJ);
    k_gemm1 <<<dim3(32, 16),    256, 0, stream>>>(X, W1tH, W1tL, B1, Hh, Hl);
    k_gemm2 <<<dim3(32, 4, 2),  256, 0, stream>>>(Hh, Hl, W2tH, W2tL, P);
    k_norm  <<<dim3(4096),      256, 0, stream>>>(P, B2, Zo, Zbh, Zbl, acc);
    k_gemm3 <<<dim3(32, 32),    256, 0, stream>>>(Zbh, Zbl, LS, LB, Lg, acc);
    k_finalize<<<1, 1, 0, stream>>>(acc, loss);
}